// Round 3
// baseline (467.932 us; speedup 1.0000x reference)
//
#include <hip/hip_runtime.h>

#define U 256       // unknown node count
#define NN 1024     // total nodes
#define NROWS 32768 // B*T rows
#define LCAP 32     // capacity of "less" (earlier-unknown-neighbor) list per node
#define DUMMY 256   // padded index -> zero/neutral slot

typedef __bf16 bf16_t;
typedef __bf16 bf16x8 __attribute__((ext_vector_type(8)));
typedef float f32x4 __attribute__((ext_vector_type(4)));
typedef unsigned short u16;
typedef unsigned short u16x8 __attribute__((ext_vector_type(8)));
typedef short s16x4 __attribute__((ext_vector_type(4)));

// ---------------------------------------------------------------------------
// K0: per unknown node k (one block each): deg, 1/deg, coef, less-list
// (ushort, padded with DUMMY). Block 0 also builds uflag + pmap.
// ---------------------------------------------------------------------------
__global__ __launch_bounds__(256) void k_struct(const float* __restrict__ A,
    const int* __restrict__ unknown, const float* __restrict__ maskp,
    float* __restrict__ invDeg, float* __restrict__ coef,
    int* __restrict__ lessCnt, u16* __restrict__ lessIdx,
    int* __restrict__ uflag, short* __restrict__ pmap)
{
    __shared__ int sunk[U];
    __shared__ float sdeg;
    __shared__ int scnt, sge;
    int t = threadIdx.x, k = blockIdx.x;
    sunk[t] = unknown[t];
    if (t == 0) { sdeg = 0.f; scnt = 0; sge = 0; }
    __syncthreads();
    int uk = sunk[k];
    float dsum = 0.f;
    for (int i = 0; i < NN / 256; ++i) {
        int n = t + 256 * i;
        float a = A[(size_t)uk * NN + n];
        if (a != 0.f) {
            dsum += a;
            int lo = 0, hi = U;
            while (lo < hi) { int mid = (lo + hi) >> 1; if (sunk[mid] < n) lo = mid + 1; else hi = mid; }
            if (lo < U && sunk[lo] == n) {
                if (lo < k) {
                    int id = atomicAdd(&scnt, 1);
                    if (id < LCAP) lessIdx[k * LCAP + id] = (u16)lo;
                } else {
                    atomicAdd(&sge, 1);
                }
            }
        }
    }
    atomicAdd(&sdeg, dsum);
    __syncthreads();
    int c0 = min(scnt, LCAP);
    if (t >= c0 && t < LCAP) lessIdx[k * LCAP + t] = DUMMY;   // pad
    if (t == 0) {
        float inv = 1.f / sdeg;
        invDeg[k] = inv;
        coef[k] = (float)sge * maskp[0] * inv;
        lessCnt[k] = c0;
    }
    if (k == 0) {
        for (int i = 0; i < NN / 256; ++i) { uflag[t + 256 * i] = 0; pmap[t + 256 * i] = -1; }
        __syncthreads();
        uflag[sunk[t]] = 1;
        pmap[sunk[t]] = (short)t;
    }
}

// ---------------------------------------------------------------------------
// K0b: topological levels (Jacobi to fixpoint; own pred-lists in registers)
// + counting sort -> order[], levelStart[], nLev.
// ---------------------------------------------------------------------------
__global__ __launch_bounds__(256) void k_levels(const int* __restrict__ lessCnt,
    const u16* __restrict__ lessIdx, int* __restrict__ order,
    int* __restrict__ levelStart, int* __restrict__ nLevOut)
{
    __shared__ u16 sIdx[U * LCAP];
    __shared__ int slvl[U + 1];
    __shared__ int hist[U];
    __shared__ int changed;
    int t = threadIdx.x;
    for (int i = t; i < U * LCAP / 2; i += 256) ((unsigned*)sIdx)[i] = ((const unsigned*)lessIdx)[i];
    int cnt = lessCnt[t];
    slvl[t] = 0; hist[t] = 0;
    if (t == 0) slvl[U] = -1;     // dummy slot: contributes level 0, neutral
    __syncthreads();
    u16x8 jv[4];
    #pragma unroll
    for (int b = 0; b < 4; ++b) jv[b] = *(const u16x8*)(&sIdx[t * LCAP + b * 8]);
    int nb = (cnt + 7) >> 3;
    int lvl = 0;
    for (int iter = 0; iter < U; ++iter) {
        if (t == 0) changed = 0;
        __syncthreads();
        int nl = 0;
        for (int b = 0; b < nb; ++b) {
            u16x8 j = jv[b];
            int m0 = max(slvl[j[0]], slvl[j[1]]);
            int m1 = max(slvl[j[2]], slvl[j[3]]);
            int m2 = max(slvl[j[4]], slvl[j[5]]);
            int m3 = max(slvl[j[6]], slvl[j[7]]);
            nl = max(nl, max(max(m0, m1), max(m2, m3)) + 1);
        }
        if (nl > lvl) { lvl = nl; slvl[t] = nl; changed = 1; }
        __syncthreads();
        if (!changed) break;
    }
    atomicAdd(&hist[lvl], 1);
    __syncthreads();
    if (t == 0) {
        int acc = 0, lastl = 0;
        for (int l = 0; l < U; ++l) {
            int h = hist[l];
            hist[l] = acc;
            acc += h;
            if (h > 0) lastl = l;
        }
        nLevOut[0] = lastl + 1;
    }
    __syncthreads();
    levelStart[t] = hist[t];
    if (t == 0) levelStart[U] = U;
    __syncthreads();
    int pos = atomicAdd(&hist[lvl], 1);
    order[pos] = t;
}

// ---------------------------------------------------------------------------
// K1: direct level-parallel forward substitution on W ROWS (no M matrix):
//   W[k][d] = invDeg[k]*( A[unknown[k]][d]*isknown(d) + sum_{j in less(k)} W[j][d] )
// Unknown-d columns stay exactly 0 by induction. 16 blocks x 64 cols,
// W-slice in fp32 LDS; 4 nodes of a level concurrently (64 lanes each).
// Block 16 runs the scalar chain bvec[k] = coef[k] + invDeg[k]*sum bvec[less].
// ---------------------------------------------------------------------------
__global__ __launch_bounds__(256) void k_wsub(const float* __restrict__ A,
    const int* __restrict__ unknown, const float* __restrict__ invDeg,
    const float* __restrict__ coef, const int* __restrict__ uflag,
    const int* __restrict__ lessCnt, const u16* __restrict__ lessIdx,
    const int* __restrict__ order, const int* __restrict__ levelStart,
    const int* __restrict__ nLevp, bf16_t* __restrict__ Wb, float* __restrict__ bvec)
{
    int t = threadIdx.x;
    int nLev = nLevp[0];
    if (blockIdx.x == 16) {
        __shared__ float sbv[U + 1];
        __shared__ u16 bIdx[U * LCAP];
        __shared__ int bLs[U + 1];
        __shared__ u16 bOrd[U];
        __shared__ float bcf[U], biv[U];
        __shared__ unsigned char bCnt[U];
        for (int i = t; i < U * LCAP / 2; i += 256) ((unsigned*)bIdx)[i] = ((const unsigned*)lessIdx)[i];
        bcf[t] = coef[t]; biv[t] = invDeg[t];
        bCnt[t] = (unsigned char)lessCnt[t];
        bOrd[t] = (u16)order[t];
        bLs[t] = levelStart[t];
        if (t == 0) { bLs[U] = levelStart[U]; sbv[U] = 0.f; }
        __syncthreads();
        for (int lev = 0; lev < nLev; ++lev) {
            int s = bLs[lev], e = bLs[lev + 1];
            int idx = s + t;
            if (idx < e) {
                int k = bOrd[idx];
                int cn = bCnt[k];
                float sum = 0.f;
                for (int b = 0; b < cn; b += 8) {
                    u16x8 j = *(const u16x8*)(&bIdx[k * LCAP + b]);
                    sum += ((sbv[j[0]] + sbv[j[1]]) + (sbv[j[2]] + sbv[j[3]]))
                         + ((sbv[j[4]] + sbv[j[5]]) + (sbv[j[6]] + sbv[j[7]]));
                }
                sbv[k] = bcf[k] + biv[k] * sum;
            }
            __syncthreads();
        }
        bvec[t] = sbv[t];
        return;
    }
    // W-substitution blocks: cols cb..cb+63
    __shared__ float Wl[(U + 1) * 64];    // 65.8 KB, row U = zeros (dummy)
    __shared__ u16 sIdx[U * LCAP];        // 16 KB
    __shared__ int sunk[U];
    __shared__ float siv[U];
    __shared__ u16 sOrd[U];
    __shared__ unsigned char sCnt[U];
    __shared__ int sLs[U + 1];
    int g = t >> 6, c = t & 63;
    int cb = blockIdx.x * 64;
    for (int i = t; i < U * LCAP / 2; i += 256) ((unsigned*)sIdx)[i] = ((const unsigned*)lessIdx)[i];
    sunk[t] = unknown[t];
    siv[t] = invDeg[t];
    sOrd[t] = (u16)order[t];
    sCnt[t] = (unsigned char)lessCnt[t];
    sLs[t] = levelStart[t];
    if (t == 0) sLs[U] = levelStart[U];
    if (t < 64) Wl[U * 64 + t] = 0.f;
    float kmask = uflag[cb + c] ? 0.f : 1.f;   // zero out unknown columns
    __syncthreads();
    for (int lev = 0; lev < nLev; ++lev) {
        int s = sLs[lev], e = sLs[lev + 1];
        for (int idx = s + g; idx < e; idx += 4) {
            int k = sOrd[idx];
            float av = A[(size_t)sunk[k] * NN + cb + c];   // L2/L3-hot
            int cn = sCnt[k];
            float sum = 0.f;
            for (int b = 0; b < cn; b += 8) {
                u16x8 j = *(const u16x8*)(&sIdx[k * LCAP + b]);
                sum += ((Wl[j[0] * 64 + c] + Wl[j[1] * 64 + c]) + (Wl[j[2] * 64 + c] + Wl[j[3] * 64 + c]))
                     + ((Wl[j[4] * 64 + c] + Wl[j[5] * 64 + c]) + (Wl[j[6] * 64 + c] + Wl[j[7] * 64 + c]));
            }
            float wv = siv[k] * (av * kmask + sum);
            Wl[k * 64 + c] = wv;
            Wb[(size_t)k * NN + cb + c] = (bf16_t)wv;
        }
        __syncthreads();
    }
}

// ---------------------------------------------------------------------------
// K3: barrier-free K-loop GEMM. A-fragments straight from x (fp32->bf16 cvt,
// 128B-aligned segments, L1-served across the 4 waves), B-fragments straight
// from Wb (L2-resident). NO LDS and NO __syncthreads until the epilogue.
// Epilogue: stage acc in LDS, merged single-pass write (re-read x, L3-hot).
// ---------------------------------------------------------------------------
#define RT 32
#define URS 257     // Ures row stride (f32): odd -> conflict-light

__global__ __launch_bounds__(256) void k_main(const float* __restrict__ x,
    const short* __restrict__ pmap, const bf16_t* __restrict__ Wb,
    const float* __restrict__ bvec, float* __restrict__ out)
{
    __shared__ __align__(16) float Ures[RT * URS];   // 32896 B
    __shared__ float sb[U];
    __shared__ short spm[NN];
    int t = threadIdx.x;
    int w = t >> 6, l = t & 63;
    int m = l & 15, q = l >> 4;
    size_t row0 = (size_t)blockIdx.x * RT;
    sb[t] = bvec[t];
    #pragma unroll
    for (int j = 0; j < 4; ++j) spm[t + 256 * j] = pmap[t + 256 * j];
    f32x4 acc[2][4] = {};
    const float* xp0 = x + (row0 + m) * NN + q * 8;          // R=0 rows m
    const float* xp1 = x + (row0 + 16 + m) * NN + q * 8;     // R=1 rows 16+m
    const bf16_t* wp0 = Wb + (size_t)((w * 4 + 0) * 16 + m) * NN + q * 8;
    const bf16_t* wp1 = Wb + (size_t)((w * 4 + 1) * 16 + m) * NN + q * 8;
    const bf16_t* wp2 = Wb + (size_t)((w * 4 + 2) * 16 + m) * NN + q * 8;
    const bf16_t* wp3 = Wb + (size_t)((w * 4 + 3) * 16 + m) * NN + q * 8;
    for (int db = 0; db < NN; db += 32) {
        bf16x8 af[2];
        {
            float4 v0 = *(const float4*)(xp0 + db);
            float4 v1 = *(const float4*)(xp0 + db + 4);
            af[0] = bf16x8{(bf16_t)v0.x, (bf16_t)v0.y, (bf16_t)v0.z, (bf16_t)v0.w,
                           (bf16_t)v1.x, (bf16_t)v1.y, (bf16_t)v1.z, (bf16_t)v1.w};
            float4 v2 = *(const float4*)(xp1 + db);
            float4 v3 = *(const float4*)(xp1 + db + 4);
            af[1] = bf16x8{(bf16_t)v2.x, (bf16_t)v2.y, (bf16_t)v2.z, (bf16_t)v2.w,
                           (bf16_t)v3.x, (bf16_t)v3.y, (bf16_t)v3.z, (bf16_t)v3.w};
        }
        bf16x8 b0 = *(const bf16x8*)(wp0 + db);
        bf16x8 b1 = *(const bf16x8*)(wp1 + db);
        bf16x8 b2 = *(const bf16x8*)(wp2 + db);
        bf16x8 b3 = *(const bf16x8*)(wp3 + db);
        acc[0][0] = __builtin_amdgcn_mfma_f32_16x16x32_bf16(af[0], b0, acc[0][0], 0, 0, 0);
        acc[1][0] = __builtin_amdgcn_mfma_f32_16x16x32_bf16(af[1], b0, acc[1][0], 0, 0, 0);
        acc[0][1] = __builtin_amdgcn_mfma_f32_16x16x32_bf16(af[0], b1, acc[0][1], 0, 0, 0);
        acc[1][1] = __builtin_amdgcn_mfma_f32_16x16x32_bf16(af[1], b1, acc[1][1], 0, 0, 0);
        acc[0][2] = __builtin_amdgcn_mfma_f32_16x16x32_bf16(af[0], b2, acc[0][2], 0, 0, 0);
        acc[1][2] = __builtin_amdgcn_mfma_f32_16x16x32_bf16(af[1], b2, acc[1][2], 0, 0, 0);
        acc[0][3] = __builtin_amdgcn_mfma_f32_16x16x32_bf16(af[0], b3, acc[0][3], 0, 0, 0);
        acc[1][3] = __builtin_amdgcn_mfma_f32_16x16x32_bf16(af[1], b3, acc[1][3], 0, 0, 0);
    }
    __syncthreads();   // sb/spm visible; Ures region untouched so far
    // stage acc (+bias) into Ures[r][u]; C/D layout: row=q*4+i, col=m
    #pragma unroll
    for (int R = 0; R < 2; ++R) {
        #pragma unroll
        for (int T = 0; T < 4; ++T) {
            int u = (w * 4 + T) * 16 + m;
            float bb = sb[u];
            #pragma unroll
            for (int i = 0; i < 4; ++i)
                Ures[(R * 16 + q * 4 + i) * URS + u] = acc[R][T][i] + bb;
        }
    }
    __syncthreads();
    // merged single-pass write: re-read x (L3-hot), substitute unknown cols
    s16x4 pm = *(const s16x4*)(&spm[t * 4]);
    #pragma unroll 4
    for (int i = 0; i < RT; ++i) {
        float4 v = *(const float4*)(x + (row0 + i) * NN + t * 4);
        if (pm[0] >= 0) v.x = Ures[i * URS + pm[0]];
        if (pm[1] >= 0) v.y = Ures[i * URS + pm[1]];
        if (pm[2] >= 0) v.z = Ures[i * URS + pm[2]];
        if (pm[3] >= 0) v.w = Ures[i * URS + pm[3]];
        *(float4*)(out + (row0 + i) * NN + t * 4) = v;
    }
}

// ---------------------------------------------------------------------------
extern "C" void kernel_launch(void* const* d_in, const int* in_sizes, int n_in,
                              void* d_out, int out_size, void* d_ws, size_t ws_size,
                              hipStream_t stream)
{
    const float* x       = (const float*)d_in[0];
    const float* A       = (const float*)d_in[1];
    const int*   unknown = (const int*)d_in[2];
    const float* maskp   = (const float*)d_in[3];
    float* out = (float*)d_out;

    char* ws = (char*)d_ws;
    bf16_t* Wb        = (bf16_t*)(ws + 0);       // 524288 B
    float*  invDeg    = (float*)(ws + 524288);
    float*  coef      = (float*)(ws + 525312);
    float*  bvec      = (float*)(ws + 526336);
    int*    lessCnt   = (int*)(ws + 527360);
    u16*    lessIdx   = (u16*)(ws + 528384);     // 16384 B
    int*    uflag     = (int*)(ws + 544768);     // 4096 B
    short*  pmap      = (short*)(ws + 548864);   // 2048 B
    int*    order     = (int*)(ws + 550912);     // 1024 B
    int*    levelStart= (int*)(ws + 551936);     // 1040 B
    int*    nLev      = (int*)(ws + 553984);

    hipLaunchKernelGGL(k_struct, dim3(U), dim3(256), 0, stream,
                       A, unknown, maskp, invDeg, coef, lessCnt, lessIdx, uflag, pmap);
    hipLaunchKernelGGL(k_levels, dim3(1), dim3(256), 0, stream,
                       lessCnt, lessIdx, order, levelStart, nLev);
    hipLaunchKernelGGL(k_wsub, dim3(17), dim3(256), 0, stream,
                       A, unknown, invDeg, coef, uflag, lessCnt, lessIdx,
                       order, levelStart, nLev, Wb, bvec);
    hipLaunchKernelGGL(k_main, dim3(NROWS / RT), dim3(256), 0, stream,
                       x, pmap, Wb, bvec, out);
}